// Round 1
// baseline (111.101 us; speedup 1.0000x reference)
//
#include <hip/hip_runtime.h>
#include <stdint.h>

#define N 4096
#define BM 128
#define BN 128
#define BK 64
#define TILES 32   // N/BM
#define NUPPER 528 // TILES*(TILES+1)/2
#define NGRID 1024 // TILES*TILES

typedef __attribute__((ext_vector_type(8))) short s16x8;
typedef __attribute__((ext_vector_type(4))) float f32x4;

// round-to-nearest-even fp32 -> bf16
__device__ __forceinline__ unsigned short f2bf(float f) {
  union { float f; unsigned int u; } c; c.f = f;
  unsigned int u = c.u;
  unsigned int r = (u + 0x7fffu + ((u >> 16) & 1u)) >> 16;
  return (unsigned short)r;
}

__device__ __forceinline__ void gld16(const void* g, void* l) {
  __builtin_amdgcn_global_load_lds(
      (const __attribute__((address_space(1))) unsigned int*)g,
      (__attribute__((address_space(3))) unsigned int*)l,
      16, 0, 0);
}

// Prepass A: bf16 convert + tril mask, row-major [row][k]
__global__ void convA(const float* __restrict__ A, unsigned short* __restrict__ Abf) {
  long idx = (long)blockIdx.x * 256 + threadIdx.x;
  long base = idx * 8;
  int row = (int)(base >> 12);
  int k0 = (int)(base & 4095);
  const float4* src = reinterpret_cast<const float4*>(A + base);
  float4 v0 = src[0], v1 = src[1];
  float vs[8] = {v0.x, v0.y, v0.z, v0.w, v1.x, v1.y, v1.z, v1.w};
  unsigned int w[4];
#pragma unroll
  for (int i = 0; i < 4; i++) {
    unsigned int lo = (k0 + 2*i     <= row) ? f2bf(vs[2*i])     : 0u;
    unsigned int hi = (k0 + 2*i + 1 <= row) ? f2bf(vs[2*i + 1]) : 0u;
    w[i] = lo | (hi << 16);
  }
  uint4 o; o.x = w[0]; o.y = w[1]; o.z = w[2]; o.w = w[3];
  *reinterpret_cast<uint4*>(Abf + base) = o;
}

// Prepass B: bf16 convert + triu mask + transpose -> Bt[col][k]
__global__ void convB(const float* __restrict__ B, unsigned short* __restrict__ Bt) {
  __shared__ unsigned short lds[64][72];  // +8 pad breaks transpose conflicts
  int t = threadIdx.x;
  int k0 = blockIdx.x * 64, c0 = blockIdx.y * 64;
#pragma unroll
  for (int p = 0; p < 4; p++) {
    int kl = p * 16 + (t >> 4);
    int cl = (t & 15) * 4;
    float4 v = *reinterpret_cast<const float4*>(B + (long)(k0 + kl) * N + c0 + cl);
    float vs[4] = {v.x, v.y, v.z, v.w};
#pragma unroll
    for (int i = 0; i < 4; i++)
      lds[kl][cl + i] = (k0 + kl <= c0 + cl + i) ? f2bf(vs[i]) : (unsigned short)0;
  }
  __syncthreads();
#pragma unroll
  for (int p = 0; p < 4; p++) {
    int cl = p * 16 + (t >> 4);
    int kl = (t & 15) * 4;
    ushort4 o;
    o.x = lds[kl + 0][cl]; o.y = lds[kl + 1][cl];
    o.z = lds[kl + 2][cl]; o.w = lds[kl + 3][cl];
    *reinterpret_cast<ushort4*>(Bt + (long)(c0 + cl) * N + k0 + kl) = o;
  }
}

// Triangular bf16 MFMA GEMM: C = triu(Abf @ Bt^T), Abf pre-masked tril, Bt pre-masked triu (transposed)
__global__ __launch_bounds__(256) void trigemm(
    const unsigned short* __restrict__ Abf,
    const unsigned short* __restrict__ Bt,
    float* __restrict__ C) {
  __shared__ unsigned short lA[BM * BK];  // [128][64] bf16, 16B-chunk XOR swizzled
  __shared__ unsigned short lB[BN * BK];

  int t = threadIdx.x;
  int lane = t & 63, wave = t >> 6;

  // linear block -> (bi,bj): heavy-first (LPT) for the 528 upper tiles, then 496 lower zero tiles
  int b = blockIdx.x;
  int bi, bj;
  bool upper;
  if (b < NUPPER) {
    upper = true;
    int r = TILES - 1, acc = 0;
    while (b >= acc + (TILES - r)) { acc += TILES - r; --r; }
    bi = r; bj = r + (b - acc);
  } else {
    upper = false;
    int u = b - NUPPER;
    int r = 1, acc = 0;
    while (u >= acc + r) { acc += r; ++r; }
    bi = r; bj = u - acc;
  }

  if (!upper) {
    // below diagonal: output is zero (d_out is poisoned -> must write)
    float4 z = make_float4(0.f, 0.f, 0.f, 0.f);
#pragma unroll
    for (int i = 0; i < 16; i++) {
      int pos = i * 256 + t;
      int row = pos >> 5, c4 = pos & 31;
      *reinterpret_cast<float4*>(C + (long)(bi * BM + row) * N + bj * BN + c4 * 4) = z;
    }
    return;
  }

  int row0 = bi * BM, col0 = bj * BN;
  int nk = (bi + 1) * (128 / BK);  // K extent = (bi+1)*128

  // staging addressing: per issue i (4 each for A,B), 256 thr x 16B = 4KB = 32 rows x 128B
  int r8 = wave * 8 + (lane >> 3);   // row_local base (+32*i per issue)
  int kc = lane & 7;                  // 16B chunk within 128B row
  int kcs = kc ^ (r8 & 7);            // inverse-swizzled source chunk (i*32 doesn't change row&7)
  const unsigned short* gA = Abf + (long)(row0 + r8) * N + kcs * 8;
  const unsigned short* gB = Bt  + (long)(col0 + r8) * N + kcs * 8;
  unsigned short* sA = lA + r8 * BK + kc * 8;  // == waveBase + lane*16B (linear dest)
  unsigned short* sB = lB + r8 * BK + kc * 8;

  f32x4 acc[4][4];
#pragma unroll
  for (int m = 0; m < 4; m++)
#pragma unroll
    for (int n = 0; n < 4; n++)
      acc[m][n] = (f32x4){0.f, 0.f, 0.f, 0.f};

  int l15 = lane & 15, l4 = lane >> 4;
  int wr = wave >> 1, wc = wave & 1;

  for (int kt = 0; kt < nk; ++kt) {
    long kof = (long)kt * BK;
#pragma unroll
    for (int i = 0; i < 4; i++) {
      gld16(gA + (long)i * 32 * N + kof, sA + i * 32 * BK);
      gld16(gB + (long)i * 32 * N + kof, sB + i * 32 * BK);
    }
    asm volatile("s_waitcnt vmcnt(0)" ::: "memory");
    __syncthreads();

#pragma unroll
    for (int kk = 0; kk < 2; kk++) {
      s16x8 af[4], bf[4];
#pragma unroll
      for (int m = 0; m < 4; m++) {
        int row = wr * 64 + m * 16 + l15;
        int lin = row * BK + kk * 32 + l4 * 8;       // element units (8 elems = 16B chunk)
        int addr = lin ^ ((row & 7) << 3);           // byte swizzle ((row&7)<<4) in elems
        af[m] = *reinterpret_cast<const s16x8*>(&lA[addr]);
      }
#pragma unroll
      for (int n = 0; n < 4; n++) {
        int col = wc * 64 + n * 16 + l15;
        int lin = col * BK + kk * 32 + l4 * 8;
        int addr = lin ^ ((col & 7) << 3);
        bf[n] = *reinterpret_cast<const s16x8*>(&lB[addr]);
      }
#pragma unroll
      for (int m = 0; m < 4; m++)
#pragma unroll
        for (int n = 0; n < 4; n++)
          acc[m][n] = __builtin_amdgcn_mfma_f32_16x16x32_bf16(af[m], bf[n], acc[m][n], 0, 0, 0);
    }
    __syncthreads();
  }

  // epilogue: C/D layout col=lane&15, row=(lane>>4)*4+reg (m89-verified)
  bool diag = (bi == bj);
#pragma unroll
  for (int m = 0; m < 4; m++) {
    int rowb = row0 + wr * 64 + m * 16 + l4 * 4;
#pragma unroll
    for (int n = 0; n < 4; n++) {
      int col = col0 + wc * 64 + n * 16 + l15;
#pragma unroll
      for (int r = 0; r < 4; r++) {
        int row = rowb + r;
        float v = acc[m][n][r];
        if (diag && row > col) v = 0.f;
        C[(long)row * N + col] = v;
      }
    }
  }
}

extern "C" void kernel_launch(void* const* d_in, const int* in_sizes, int n_in,
                              void* d_out, int out_size, void* d_ws, size_t ws_size,
                              hipStream_t stream) {
  const float* A = (const float*)d_in[0];
  const float* B = (const float*)d_in[1];
  float* C = (float*)d_out;
  // workspace: Abf (32MB) + Bt (32MB), both bf16 4096x4096
  unsigned short* Abf = (unsigned short*)d_ws;
  unsigned short* Bt = Abf + (size_t)N * N;

  convA<<<dim3(N * (N / 8) / 256), dim3(256), 0, stream>>>(A, Abf);
  convB<<<dim3(N / 64, N / 64), dim3(256), 0, stream>>>(B, Bt);
  trigemm<<<dim3(NGRID), dim3(256), 0, stream>>>(Abf, Bt, C);
}

// Round 2
// 102.217 us; speedup vs baseline: 1.0869x; 1.0869x over previous
//
#include <hip/hip_runtime.h>
#include <stdint.h>

#define N 4096
#define BM 128
#define BN 128
#define BK 64
#define TILES 32   // N/BM
#define NUPPER 528 // TILES*(TILES+1)/2
#define NGRID 1024 // TILES*TILES

typedef __attribute__((ext_vector_type(8))) short s16x8;
typedef __attribute__((ext_vector_type(4))) float f32x4;

// round-to-nearest-even fp32 -> bf16
__device__ __forceinline__ unsigned short f2bf(float f) {
  union { float f; unsigned int u; } c; c.f = f;
  unsigned int u = c.u;
  unsigned int r = (u + 0x7fffu + ((u >> 16) & 1u)) >> 16;
  return (unsigned short)r;
}

__device__ __forceinline__ void gld16(const void* g, void* l) {
  __builtin_amdgcn_global_load_lds(
      (const __attribute__((address_space(1))) unsigned int*)g,
      (__attribute__((address_space(3))) unsigned int*)l,
      16, 0, 0);
}

// Prepass A: bf16 convert + tril mask, row-major [row][k]
__global__ void convA(const float* __restrict__ A, unsigned short* __restrict__ Abf) {
  long idx = (long)blockIdx.x * 256 + threadIdx.x;
  long base = idx * 8;
  int row = (int)(base >> 12);
  int k0 = (int)(base & 4095);
  const float4* src = reinterpret_cast<const float4*>(A + base);
  float4 v0 = src[0], v1 = src[1];
  float vs[8] = {v0.x, v0.y, v0.z, v0.w, v1.x, v1.y, v1.z, v1.w};
  unsigned int w[4];
#pragma unroll
  for (int i = 0; i < 4; i++) {
    unsigned int lo = (k0 + 2*i     <= row) ? f2bf(vs[2*i])     : 0u;
    unsigned int hi = (k0 + 2*i + 1 <= row) ? f2bf(vs[2*i + 1]) : 0u;
    w[i] = lo | (hi << 16);
  }
  uint4 o; o.x = w[0]; o.y = w[1]; o.z = w[2]; o.w = w[3];
  *reinterpret_cast<uint4*>(Abf + base) = o;
}

// Prepass B: bf16 convert + triu mask + transpose -> Bt[col][k]
__global__ void convB(const float* __restrict__ B, unsigned short* __restrict__ Bt) {
  __shared__ unsigned short lds[64][72];  // +8 pad breaks transpose conflicts
  int t = threadIdx.x;
  int k0 = blockIdx.x * 64, c0 = blockIdx.y * 64;
#pragma unroll
  for (int p = 0; p < 4; p++) {
    int kl = p * 16 + (t >> 4);
    int cl = (t & 15) * 4;
    float4 v = *reinterpret_cast<const float4*>(B + (long)(k0 + kl) * N + c0 + cl);
    float vs[4] = {v.x, v.y, v.z, v.w};
#pragma unroll
    for (int i = 0; i < 4; i++)
      lds[kl][cl + i] = (k0 + kl <= c0 + cl + i) ? f2bf(vs[i]) : (unsigned short)0;
  }
  __syncthreads();
#pragma unroll
  for (int p = 0; p < 4; p++) {
    int cl = p * 16 + (t >> 4);
    int kl = (t & 15) * 4;
    ushort4 o;
    o.x = lds[kl + 0][cl]; o.y = lds[kl + 1][cl];
    o.z = lds[kl + 2][cl]; o.w = lds[kl + 3][cl];
    *reinterpret_cast<ushort4*>(Bt + (long)(c0 + cl) * N + k0 + kl) = o;
  }
}

// Triangular bf16 MFMA GEMM: C = triu(Abf @ Bt^T), Abf pre-masked tril, Bt pre-masked triu (transposed)
// 2-phase double-buffered pipeline (T3 minimum): stage next k-tile before computing current,
// counted s_waitcnt vmcnt(8) + raw s_barrier (no vmcnt(0) drain in loop).
__global__ __launch_bounds__(256) void trigemm(
    const unsigned short* __restrict__ Abf,
    const unsigned short* __restrict__ Bt,
    float* __restrict__ C) {
  __shared__ unsigned short lA[2][BM * BK];  // 2 x 16KB, 16B-chunk XOR swizzled
  __shared__ unsigned short lB[2][BN * BK];  // 2 x 16KB

  int t = threadIdx.x;
  int lane = t & 63, wave = t >> 6;

  // linear block -> (bi,bj): heavy-first (LPT) for the 528 upper tiles, then 496 lower zero tiles
  int b = blockIdx.x;
  int bi, bj;
  bool upper;
  if (b < NUPPER) {
    upper = true;
    int r = TILES - 1, acc = 0;
    while (b >= acc + (TILES - r)) { acc += TILES - r; --r; }
    bi = r; bj = r + (b - acc);
  } else {
    upper = false;
    int u = b - NUPPER;
    int r = 1, acc = 0;
    while (u >= acc + r) { acc += r; ++r; }
    bi = r; bj = u - acc;
  }

  if (!upper) {
    // below diagonal: output is zero (d_out is poisoned -> must write)
    float4 z = make_float4(0.f, 0.f, 0.f, 0.f);
#pragma unroll
    for (int i = 0; i < 16; i++) {
      int pos = i * 256 + t;
      int row = pos >> 5, c4 = pos & 31;
      *reinterpret_cast<float4*>(C + (long)(bi * BM + row) * N + bj * BN + c4 * 4) = z;
    }
    return;
  }

  int row0 = bi * BM, col0 = bj * BN;
  int nk = (bi + 1) * (128 / BK);  // K extent = (bi+1)*128

  // staging addressing: per issue i (4 each for A,B), 256 thr x 16B = 4KB = 32 rows x 128B
  int r8 = wave * 8 + (lane >> 3);   // row_local base (+32*i per issue)
  int kc = lane & 7;                  // 16B chunk within 128B row
  int kcs = kc ^ (r8 & 7);            // inverse-swizzled source chunk (i*32 doesn't change row&7)
  const unsigned short* gA = Abf + (long)(row0 + r8) * N + kcs * 8;
  const unsigned short* gB = Bt  + (long)(col0 + r8) * N + kcs * 8;
  unsigned short* sA = &lA[0][0] + r8 * BK + kc * 8;  // linear dest = waveBase + lane*16B
  unsigned short* sB = &lB[0][0] + r8 * BK + kc * 8;

  f32x4 acc[4][4];
#pragma unroll
  for (int m = 0; m < 4; m++)
#pragma unroll
    for (int n = 0; n < 4; n++)
      acc[m][n] = (f32x4){0.f, 0.f, 0.f, 0.f};

  int l15 = lane & 15, l4 = lane >> 4;
  int wr = wave >> 1, wc = wave & 1;

  // prologue: stage k-tile 0 into buffer 0
  {
#pragma unroll
    for (int i = 0; i < 4; i++) {
      gld16(gA + (long)i * 32 * N, sA + i * 32 * BK);
      gld16(gB + (long)i * 32 * N, sB + i * 32 * BK);
    }
  }

  int cur = 0;
  for (int kt = 0; kt < nk; ++kt) {
    if (kt + 1 < nk) {
      // issue next tile's loads into the other buffer (8 vmem ops)
      long kof = (long)(kt + 1) * BK;
      int nb = cur ^ 1;
#pragma unroll
      for (int i = 0; i < 4; i++) {
        gld16(gA + (long)i * 32 * N + kof, sA + nb * (BM * BK) + i * 32 * BK);
        gld16(gB + (long)i * 32 * N + kof, sB + nb * (BN * BK) + i * 32 * BK);
      }
      asm volatile("s_waitcnt vmcnt(8)" ::: "memory");  // current buffer's 8 loads done
    } else {
      asm volatile("s_waitcnt vmcnt(0)" ::: "memory");
    }
    __builtin_amdgcn_s_barrier();

    const unsigned short* bA = &lA[0][0] + cur * (BM * BK);
    const unsigned short* bB = &lB[0][0] + cur * (BN * BK);
#pragma unroll
    for (int kk = 0; kk < 2; kk++) {
      s16x8 af[4], bf[4];
#pragma unroll
      for (int m = 0; m < 4; m++) {
        int row = wr * 64 + m * 16 + l15;
        int lin = row * BK + kk * 32 + l4 * 8;       // element units (8 elems = 16B chunk)
        int addr = lin ^ ((row & 7) << 3);           // byte swizzle ((row&7)<<4) in elems
        af[m] = *reinterpret_cast<const s16x8*>(&bA[addr]);
      }
#pragma unroll
      for (int n = 0; n < 4; n++) {
        int col = wc * 64 + n * 16 + l15;
        int lin = col * BK + kk * 32 + l4 * 8;
        int addr = lin ^ ((col & 7) << 3);
        bf[n] = *reinterpret_cast<const s16x8*>(&bB[addr]);
      }
#pragma unroll
      for (int m = 0; m < 4; m++)
#pragma unroll
        for (int n = 0; n < 4; n++)
          acc[m][n] = __builtin_amdgcn_mfma_f32_16x16x32_bf16(af[m], bf[n], acc[m][n], 0, 0, 0);
    }
    __builtin_amdgcn_s_barrier();
    cur ^= 1;
  }

  // epilogue: C/D layout col=lane&15, row=(lane>>4)*4+reg (m89-verified)
  bool diag = (bi == bj);
#pragma unroll
  for (int m = 0; m < 4; m++) {
    int rowb = row0 + wr * 64 + m * 16 + l4 * 4;
#pragma unroll
    for (int n = 0; n < 4; n++) {
      int col = col0 + wc * 64 + n * 16 + l15;
#pragma unroll
      for (int r = 0; r < 4; r++) {
        int row = rowb + r;
        float v = acc[m][n][r];
        if (diag && row > col) v = 0.f;
        C[(long)row * N + col] = v;
      }
    }
  }
}

extern "C" void kernel_launch(void* const* d_in, const int* in_sizes, int n_in,
                              void* d_out, int out_size, void* d_ws, size_t ws_size,
                              hipStream_t stream) {
  const float* A = (const float*)d_in[0];
  const float* B = (const float*)d_in[1];
  float* C = (float*)d_out;
  // workspace: Abf (32MB) + Bt (32MB), both bf16 4096x4096
  unsigned short* Abf = (unsigned short*)d_ws;
  unsigned short* Bt = Abf + (size_t)N * N;

  convA<<<dim3(N * (N / 8) / 256), dim3(256), 0, stream>>>(A, Abf);
  convB<<<dim3(N / 64, N / 64), dim3(256), 0, stream>>>(B, Bt);
  trigemm<<<dim3(NGRID), dim3(256), 0, stream>>>(Abf, Bt, C);
}

// Round 3
// 100.464 us; speedup vs baseline: 1.1059x; 1.0174x over previous
//
#include <hip/hip_runtime.h>
#include <stdint.h>

#define N 4096
#define BM 128
#define BN 128
#define BK 32
#define TILES 32   // N/BM
#define NUPPER 528 // TILES*(TILES+1)/2
#define NGRID 1024 // TILES*TILES

typedef __attribute__((ext_vector_type(8))) short s16x8;
typedef __attribute__((ext_vector_type(4))) float f32x4;

// round-to-nearest-even fp32 -> bf16
__device__ __forceinline__ unsigned short f2bf(float f) {
  union { float f; unsigned int u; } c; c.f = f;
  unsigned int u = c.u;
  unsigned int r = (u + 0x7fffu + ((u >> 16) & 1u)) >> 16;
  return (unsigned short)r;
}

__device__ __forceinline__ void gld16(const void* g, void* l) {
  __builtin_amdgcn_global_load_lds(
      (const __attribute__((address_space(1))) unsigned int*)g,
      (__attribute__((address_space(3))) unsigned int*)l,
      16, 0, 0);
}

// Fused prepass: A -> tril-masked bf16 (row-major), B -> triu-masked bf16 transposed.
// Skips loads/writes of regions trigemm never reads:
//   Abf[row][k] only needed for k <  ((row>>7)+1)*128
//   Bt [col][k] only needed for k <  ((col>>7)+1)*128
__global__ void prep(const float* __restrict__ A, const float* __restrict__ B,
                     unsigned short* __restrict__ Abf, unsigned short* __restrict__ Bt) {
  int bid = blockIdx.x;
  int t = threadIdx.x;
  if (bid < 8192) {
    // ---- A path: one block = half a row (2048 elems), 8 elems/thread ----
    long base = (long)bid * 2048 + (long)t * 8;
    int row = (int)(base >> 12);
    int k0 = (int)(base & 4095);
    int bound = ((row >> 7) + 1) << 7;       // first k trigemm never reads
    if (k0 >= bound) return;                  // uniform across block halves
    if (k0 > row) {
      uint4 z = make_uint4(0u, 0u, 0u, 0u);
      *reinterpret_cast<uint4*>(Abf + base) = z;
      return;
    }
    const float4* src = reinterpret_cast<const float4*>(A + base);
    float4 v0 = src[0], v1 = src[1];
    float vs[8] = {v0.x, v0.y, v0.z, v0.w, v1.x, v1.y, v1.z, v1.w};
    unsigned int w[4];
#pragma unroll
    for (int i = 0; i < 4; i++) {
      unsigned int lo = (k0 + 2*i     <= row) ? f2bf(vs[2*i])     : 0u;
      unsigned int hi = (k0 + 2*i + 1 <= row) ? f2bf(vs[2*i + 1]) : 0u;
      w[i] = lo | (hi << 16);
    }
    uint4 o; o.x = w[0]; o.y = w[1]; o.z = w[2]; o.w = w[3];
    *reinterpret_cast<uint4*>(Abf + base) = o;
  } else {
    // ---- B path: 64x64 tile transpose with triu mask ----
    int b2 = bid - 8192;
    int k0 = (b2 & 63) * 64;
    int c0 = (b2 >> 6) * 64;
    int cj = c0 >> 7;
    if (k0 >= ((cj + 1) << 7)) return;        // never read by trigemm
    if (k0 > c0 + 63) {
      // strictly below diagonal but still read: write zeros, skip load
      ushort4 z = make_ushort4(0, 0, 0, 0);
#pragma unroll
      for (int p = 0; p < 4; p++) {
        int cl = p * 16 + (t >> 4);
        int kl = (t & 15) * 4;
        *reinterpret_cast<ushort4*>(Bt + (long)(c0 + cl) * N + k0 + kl) = z;
      }
      return;
    }
    __shared__ unsigned short lds[64][72];    // +8 pad breaks transpose conflicts
#pragma unroll
    for (int p = 0; p < 4; p++) {
      int kl = p * 16 + (t >> 4);
      int cl = (t & 15) * 4;
      float4 v = *reinterpret_cast<const float4*>(B + (long)(k0 + kl) * N + c0 + cl);
      float vs[4] = {v.x, v.y, v.z, v.w};
#pragma unroll
      for (int i = 0; i < 4; i++)
        lds[kl][cl + i] = (k0 + kl <= c0 + cl + i) ? f2bf(vs[i]) : (unsigned short)0;
    }
    __syncthreads();
#pragma unroll
    for (int p = 0; p < 4; p++) {
      int cl = p * 16 + (t >> 4);
      int kl = (t & 15) * 4;
      ushort4 o;
      o.x = lds[kl + 0][cl]; o.y = lds[kl + 1][cl];
      o.z = lds[kl + 2][cl]; o.w = lds[kl + 3][cl];
      *reinterpret_cast<ushort4*>(Bt + (long)(c0 + cl) * N + k0 + kl) = o;
    }
  }
}

// Triangular bf16 MFMA GEMM: C = triu(Abf @ Bt^T).
// BK=32, double-buffered (32KB LDS -> 4 blocks/CU), counted vmcnt(4),
// snake block->tile rank mapping for static CU balance.
__global__ __launch_bounds__(256, 4) void trigemm(
    const unsigned short* __restrict__ Abf,
    const unsigned short* __restrict__ Bt,
    float* __restrict__ C) {
  __shared__ unsigned short lA[2][BM * BK];  // 2 x 8KB, 16B-chunk XOR swizzled
  __shared__ unsigned short lB[2][BN * BK];

  int t = threadIdx.x;
  int lane = t & 63, wave = t >> 6;

  // snake rank: CU tuples {b, b+256, b+512, b+768} -> ranks {k, 511-k, 512+k, 1023-k}
  int b = blockIdx.x;
  int rank = (b < 256) ? b : (b < 512) ? (767 - b) : (b < 768) ? b : (1791 - b);

  int bi, bj;
  bool upper;
  if (rank < NUPPER) {
    upper = true;  // heavy-first: bi descending
    int r = TILES - 1, acc = 0;
    while (rank >= acc + (TILES - r)) { acc += TILES - r; --r; }
    bi = r; bj = r + (rank - acc);
  } else {
    upper = false;
    int u = rank - NUPPER;
    int r = 1, acc = 0;
    while (u >= acc + r) { acc += r; ++r; }
    bi = r; bj = u - acc;
  }

  if (!upper) {
    // below diagonal: output is zero (d_out is poisoned -> must write)
    float4 z = make_float4(0.f, 0.f, 0.f, 0.f);
#pragma unroll
    for (int i = 0; i < 16; i++) {
      int pos = i * 256 + t;
      int row = pos >> 5, c4 = pos & 31;
      *reinterpret_cast<float4*>(C + (long)(bi * BM + row) * N + bj * BN + c4 * 4) = z;
    }
    return;
  }

  int row0 = bi * BM, col0 = bj * BN;
  int nk = (bi + 1) * 4;  // K extent = (bi+1)*128, BK=32

  // staging: per issue, 256 thr x 16B = 4KB = 64 rows x 64B
  int r8 = t >> 2;                    // row base 0..63 (wave-contiguous: lane*16B linear)
  int kc = t & 3;                     // 16B chunk within 64B row
  int kcs = kc ^ (r8 & 3);            // inverse-swizzled source chunk ((r8+64)&3 == r8&3)
  const unsigned short* gA = Abf + (long)(row0 + r8) * N + kcs * 8;
  const unsigned short* gB = Bt  + (long)(col0 + r8) * N + kcs * 8;
  unsigned short* sA = &lA[0][0] + r8 * BK + kc * 8;
  unsigned short* sB = &lB[0][0] + r8 * BK + kc * 8;

  f32x4 acc[4][4];
#pragma unroll
  for (int m = 0; m < 4; m++)
#pragma unroll
    for (int n = 0; n < 4; n++)
      acc[m][n] = (f32x4){0.f, 0.f, 0.f, 0.f};

  int l15 = lane & 15, l4 = lane >> 4;
  int wr = wave >> 1, wc = wave & 1;

  // prologue: stage k-tile 0 into buffer 0 (4 loads: 2 A + 2 B)
#pragma unroll
  for (int i = 0; i < 2; i++) {
    gld16(gA + (long)i * 64 * N, sA + i * 64 * BK);
    gld16(gB + (long)i * 64 * N, sB + i * 64 * BK);
  }

  int cur = 0;
  for (int kt = 0; kt < nk; ++kt) {
    if (kt + 1 < nk) {
      long kof = (long)(kt + 1) * BK;
      int nb = cur ^ 1;
#pragma unroll
      for (int i = 0; i < 2; i++) {
        gld16(gA + (long)i * 64 * N + kof, sA + nb * (BM * BK) + i * 64 * BK);
        gld16(gB + (long)i * 64 * N + kof, sB + nb * (BN * BK) + i * 64 * BK);
      }
      asm volatile("s_waitcnt vmcnt(4)" ::: "memory");  // current buffer's 4 loads done
    } else {
      asm volatile("s_waitcnt vmcnt(0)" ::: "memory");
    }
    __builtin_amdgcn_s_barrier();

    const unsigned short* bA = &lA[0][0] + cur * (BM * BK);
    const unsigned short* bB = &lB[0][0] + cur * (BN * BK);
    s16x8 af[4], bf[4];
#pragma unroll
    for (int m = 0; m < 4; m++) {
      int row = wr * 64 + m * 16 + l15;
      int addr = row * BK + ((l4 ^ (row & 3)) << 3);   // swizzled 16B chunk
      af[m] = *reinterpret_cast<const s16x8*>(&bA[addr]);
    }
#pragma unroll
    for (int n = 0; n < 4; n++) {
      int col = wc * 64 + n * 16 + l15;
      int addr = col * BK + ((l4 ^ (col & 3)) << 3);
      bf[n] = *reinterpret_cast<const s16x8*>(&bB[addr]);
    }
#pragma unroll
    for (int m = 0; m < 4; m++)
#pragma unroll
      for (int n = 0; n < 4; n++)
        acc[m][n] = __builtin_amdgcn_mfma_f32_16x16x32_bf16(af[m], bf[n], acc[m][n], 0, 0, 0);

    __builtin_amdgcn_s_barrier();
    cur ^= 1;
  }

  // epilogue: C/D layout col=lane&15, row=(lane>>4)*4+reg (m89-verified)
  bool diag = (bi == bj);
#pragma unroll
  for (int m = 0; m < 4; m++) {
    int rowb = row0 + wr * 64 + m * 16 + l4 * 4;
#pragma unroll
    for (int n = 0; n < 4; n++) {
      int col = col0 + wc * 64 + n * 16 + l15;
#pragma unroll
      for (int r = 0; r < 4; r++) {
        int row = rowb + r;
        float v = acc[m][n][r];
        if (diag && row > col) v = 0.f;
        C[(long)row * N + col] = v;
      }
    }
  }
}

extern "C" void kernel_launch(void* const* d_in, const int* in_sizes, int n_in,
                              void* d_out, int out_size, void* d_ws, size_t ws_size,
                              hipStream_t stream) {
  const float* A = (const float*)d_in[0];
  const float* B = (const float*)d_in[1];
  float* C = (float*)d_out;
  // workspace: Abf (32MB) + Bt (32MB), both bf16 4096x4096
  unsigned short* Abf = (unsigned short*)d_ws;
  unsigned short* Bt = Abf + (size_t)N * N;

  prep<<<dim3(8192 + 4096), dim3(256), 0, stream>>>(A, B, Abf, Bt);
  trigemm<<<dim3(NGRID), dim3(256), 0, stream>>>(Abf, Bt, C);
}

// Round 4
// 90.521 us; speedup vs baseline: 1.2273x; 1.1098x over previous
//
#include <hip/hip_runtime.h>
#include <stdint.h>

#define N 4096
#define BM 128
#define BN 128
#define BK 64
#define TILES 32   // N/BM
#define NUPPER 528 // TILES*(TILES+1)/2
#define NITEMS 1024 // upper items + zero items
#define NWORKERS 512 // 2 blocks/CU at 64KB LDS

typedef __attribute__((ext_vector_type(8))) short s16x8;
typedef __attribute__((ext_vector_type(4))) float f32x4;

// round-to-nearest-even fp32 -> bf16
__device__ __forceinline__ unsigned short f2bf(float f) {
  union { float f; unsigned int u; } c; c.f = f;
  unsigned int u = c.u;
  unsigned int r = (u + 0x7fffu + ((u >> 16) & 1u)) >> 16;
  return (unsigned short)r;
}

__device__ __forceinline__ void gld16(const void* g, void* l) {
  __builtin_amdgcn_global_load_lds(
      (const __attribute__((address_space(1))) unsigned int*)g,
      (__attribute__((address_space(3))) unsigned int*)l,
      16, 0, 0);
}

// Fused prepass: A -> tril-masked bf16 (row-major), B -> triu-masked bf16 transposed.
// Skips loads/writes of regions trigemm never reads. Block 0 also resets the work counter.
__global__ void prep(const float* __restrict__ A, const float* __restrict__ B,
                     unsigned short* __restrict__ Abf, unsigned short* __restrict__ Bt,
                     int* __restrict__ cnt) {
  int bid = blockIdx.x;
  int t = threadIdx.x;
  if (bid == 0 && t == 0) *cnt = 0;   // reset work queue (prep completes before trigemm starts)
  if (bid < 8192) {
    // ---- A path: one block = half a row (2048 elems), 8 elems/thread ----
    long base = (long)bid * 2048 + (long)t * 8;
    int row = (int)(base >> 12);
    int k0 = (int)(base & 4095);
    int bound = ((row >> 7) + 1) << 7;       // first k trigemm never reads
    if (k0 >= bound) return;
    if (k0 > row) {
      uint4 z = make_uint4(0u, 0u, 0u, 0u);
      *reinterpret_cast<uint4*>(Abf + base) = z;
      return;
    }
    const float4* src = reinterpret_cast<const float4*>(A + base);
    float4 v0 = src[0], v1 = src[1];
    float vs[8] = {v0.x, v0.y, v0.z, v0.w, v1.x, v1.y, v1.z, v1.w};
    unsigned int w[4];
#pragma unroll
    for (int i = 0; i < 4; i++) {
      unsigned int lo = (k0 + 2*i     <= row) ? f2bf(vs[2*i])     : 0u;
      unsigned int hi = (k0 + 2*i + 1 <= row) ? f2bf(vs[2*i + 1]) : 0u;
      w[i] = lo | (hi << 16);
    }
    uint4 o; o.x = w[0]; o.y = w[1]; o.z = w[2]; o.w = w[3];
    *reinterpret_cast<uint4*>(Abf + base) = o;
  } else {
    // ---- B path: 64x64 tile transpose with triu mask ----
    int b2 = bid - 8192;
    int k0 = (b2 & 63) * 64;
    int c0 = (b2 >> 6) * 64;
    int cj = c0 >> 7;
    if (k0 >= ((cj + 1) << 7)) return;        // never read by trigemm
    if (k0 > c0 + 63) {
      ushort4 z = make_ushort4(0, 0, 0, 0);
#pragma unroll
      for (int p = 0; p < 4; p++) {
        int cl = p * 16 + (t >> 4);
        int kl = (t & 15) * 4;
        *reinterpret_cast<ushort4*>(Bt + (long)(c0 + cl) * N + k0 + kl) = z;
      }
      return;
    }
    __shared__ unsigned short lds[64][72];    // +8 pad breaks transpose conflicts
#pragma unroll
    for (int p = 0; p < 4; p++) {
      int kl = p * 16 + (t >> 4);
      int cl = (t & 15) * 4;
      float4 v = *reinterpret_cast<const float4*>(B + (long)(k0 + kl) * N + c0 + cl);
      float vs[4] = {v.x, v.y, v.z, v.w};
#pragma unroll
      for (int i = 0; i < 4; i++)
        lds[kl][cl + i] = (k0 + kl <= c0 + cl + i) ? f2bf(vs[i]) : (unsigned short)0;
    }
    __syncthreads();
#pragma unroll
    for (int p = 0; p < 4; p++) {
      int cl = p * 16 + (t >> 4);
      int kl = (t & 15) * 4;
      ushort4 o;
      o.x = lds[kl + 0][cl]; o.y = lds[kl + 1][cl];
      o.z = lds[kl + 2][cl]; o.w = lds[kl + 3][cl];
      *reinterpret_cast<ushort4*>(Bt + (long)(c0 + cl) * N + k0 + kl) = o;
    }
  }
}

// Triangular bf16 MFMA GEMM: C = triu(Abf @ Bt^T).
// 512 persistent workers drain an atomic LPT (heavy-first) work queue.
// Per item: BK=64 double-buffered 2-phase pipeline, counted vmcnt(8), zero-conflict XOR swizzle.
__global__ __launch_bounds__(256) void trigemm(
    const unsigned short* __restrict__ Abf,
    const unsigned short* __restrict__ Bt,
    float* __restrict__ C, int* __restrict__ cnt) {
  __shared__ unsigned short lA[2][BM * BK];  // 2 x 16KB, 16B-chunk XOR swizzled
  __shared__ unsigned short lB[2][BN * BK];
  __shared__ int sh;

  int t = threadIdx.x;
  int lane = t & 63, wave = t >> 6;

  // staging addressing (item-independent part): 256 thr x 16B = 4KB = 32 rows x 128B per issue
  int r8 = wave * 8 + (lane >> 3);
  int kc = lane & 7;
  int kcs = kc ^ (r8 & 7);            // inverse-swizzled source chunk
  int l15 = lane & 15, l4 = lane >> 4;
  int wr = wave >> 1, wc = wave & 1;

  for (;;) {
    if (t == 0) sh = atomicAdd(cnt, 1);
    __syncthreads();
    int rank = sh;
    __syncthreads();          // protect sh before next iteration's write
    if (rank >= NITEMS) return;

    // rank -> (bi,bj): heavy-first for the 528 upper tiles, then 496 lower zero tiles
    int bi, bj;
    bool upper;
    if (rank < NUPPER) {
      upper = true;
      int r = TILES - 1, acc = 0;
      while (rank >= acc + (TILES - r)) { acc += TILES - r; --r; }
      bi = r; bj = r + (rank - acc);
    } else {
      upper = false;
      int u = rank - NUPPER;
      int r = 1, acc = 0;
      while (u >= acc + r) { acc += r; ++r; }
      bi = r; bj = u - acc;
    }

    if (!upper) {
      // below diagonal: output is zero (d_out is poisoned -> must write)
      float4 z = make_float4(0.f, 0.f, 0.f, 0.f);
#pragma unroll
      for (int i = 0; i < 16; i++) {
        int pos = i * 256 + t;
        int row = pos >> 5, c4 = pos & 31;
        *reinterpret_cast<float4*>(C + (long)(bi * BM + row) * N + bj * BN + c4 * 4) = z;
      }
      continue;
    }

    int row0 = bi * BM, col0 = bj * BN;
    int nk = (bi + 1) * 2;  // K extent = (bi+1)*128, BK=64

    const unsigned short* gA = Abf + (long)(row0 + r8) * N + kcs * 8;
    const unsigned short* gB = Bt  + (long)(col0 + r8) * N + kcs * 8;
    unsigned short* sA = &lA[0][0] + r8 * BK + kc * 8;
    unsigned short* sB = &lB[0][0] + r8 * BK + kc * 8;

    f32x4 acc[4][4];
#pragma unroll
    for (int m = 0; m < 4; m++)
#pragma unroll
      for (int n = 0; n < 4; n++)
        acc[m][n] = (f32x4){0.f, 0.f, 0.f, 0.f};

    // prologue: stage k-tile 0 into buffer 0 (8 loads)
#pragma unroll
    for (int i = 0; i < 4; i++) {
      gld16(gA + (long)i * 32 * N, sA + i * 32 * BK);
      gld16(gB + (long)i * 32 * N, sB + i * 32 * BK);
    }

    int cur = 0;
    for (int kt = 0; kt < nk; ++kt) {
      if (kt + 1 < nk) {
        long kof = (long)(kt + 1) * BK;
        int nb = cur ^ 1;
#pragma unroll
        for (int i = 0; i < 4; i++) {
          gld16(gA + (long)i * 32 * N + kof, sA + nb * (BM * BK) + i * 32 * BK);
          gld16(gB + (long)i * 32 * N + kof, sB + nb * (BN * BK) + i * 32 * BK);
        }
        asm volatile("s_waitcnt vmcnt(8)" ::: "memory");  // current buffer's 8 loads done
      } else {
        asm volatile("s_waitcnt vmcnt(0)" ::: "memory");
      }
      __builtin_amdgcn_s_barrier();

      const unsigned short* bA = &lA[0][0] + cur * (BM * BK);
      const unsigned short* bB = &lB[0][0] + cur * (BN * BK);
#pragma unroll
      for (int kk = 0; kk < 2; kk++) {
        s16x8 af[4], bf[4];
#pragma unroll
        for (int m = 0; m < 4; m++) {
          int row = wr * 64 + m * 16 + l15;
          int lin = row * BK + kk * 32 + l4 * 8;       // element units
          int addr = lin ^ ((row & 7) << 3);           // zero-conflict XOR swizzle
          af[m] = *reinterpret_cast<const s16x8*>(&bA[addr]);
        }
#pragma unroll
        for (int n = 0; n < 4; n++) {
          int col = wc * 64 + n * 16 + l15;
          int lin = col * BK + kk * 32 + l4 * 8;
          int addr = lin ^ ((col & 7) << 3);
          bf[n] = *reinterpret_cast<const s16x8*>(&bB[addr]);
        }
#pragma unroll
        for (int m = 0; m < 4; m++)
#pragma unroll
          for (int n = 0; n < 4; n++)
            acc[m][n] = __builtin_amdgcn_mfma_f32_16x16x32_bf16(af[m], bf[n], acc[m][n], 0, 0, 0);
      }
      __builtin_amdgcn_s_barrier();
      cur ^= 1;
    }

    // epilogue: C/D layout col=lane&15, row=(lane>>4)*4+reg (m89-verified)
    bool diag = (bi == bj);
#pragma unroll
    for (int m = 0; m < 4; m++) {
      int rowb = row0 + wr * 64 + m * 16 + l4 * 4;
#pragma unroll
      for (int n = 0; n < 4; n++) {
        int col = col0 + wc * 64 + n * 16 + l15;
#pragma unroll
        for (int r = 0; r < 4; r++) {
          int row = rowb + r;
          float v = acc[m][n][r];
          if (diag && row > col) v = 0.f;
          C[(long)row * N + col] = v;
        }
      }
    }
  }
}

extern "C" void kernel_launch(void* const* d_in, const int* in_sizes, int n_in,
                              void* d_out, int out_size, void* d_ws, size_t ws_size,
                              hipStream_t stream) {
  const float* A = (const float*)d_in[0];
  const float* B = (const float*)d_in[1];
  float* C = (float*)d_out;
  // workspace: Abf (32MB) + Bt (32MB), both bf16 4096x4096
  unsigned short* Abf = (unsigned short*)d_ws;
  unsigned short* Bt = Abf + (size_t)N * N;
  // work-queue counter hidden in a hole of Bt that trigemm never reads and prep never
  // writes: col-tile 0 only uses k<128; pick col=0, k=2048.
  int* cnt = (int*)(Bt + 2048);

  prep<<<dim3(8192 + 4096), dim3(256), 0, stream>>>(A, B, Abf, Bt, cnt);
  trigemm<<<dim3(NWORKERS), dim3(256), 0, stream>>>(Abf, Bt, C, cnt);
}